// Round 1
// baseline (472.682 us; speedup 1.0000x reference)
//
#include <hip/hip_runtime.h>
#include <hip/hip_bf16.h>

typedef unsigned short u16;
typedef unsigned int   u32;
typedef __attribute__((ext_vector_type(8))) short short8;
typedef __attribute__((ext_vector_type(4))) float floatx4;

__device__ __forceinline__ u16 f2bf(float f){
  u32 x = __float_as_uint(f);
  u32 r = (x + 0x7fffu + ((x >> 16) & 1u)) >> 16;   // RNE
  return (u16)r;
}
__device__ __forceinline__ float bf2f(u16 u){
  return __uint_as_float(((u32)u) << 16);
}

// B=64, L=1000, D=300 padded to 320; V=50000
// ---------------- K1: gather + bf16 cast, zero-pad cols [300,320) ------------
__global__ void k_gather(const int* __restrict__ idx, const float* __restrict__ emb,
                         u16* __restrict__ x, int total){
  int i = blockIdx.x * blockDim.x + threadIdx.x;
  if (i >= total) return;
  int row = i / 320; int dp = i - row * 320;
  float v = 0.f;
  if (dp < 300) v = emb[idx[row] * 300 + dp];
  x[i] = f2bf(v);
}

// ---------------- K2: segment sums (windows of r) ---------------------------
__global__ void k_segsum(const u16* __restrict__ x, u16* __restrict__ seg,
                         int r, int Lr, int total){
  int i = blockIdx.x * blockDim.x + threadIdx.x;
  if (i >= total) return;
  int ro = i / 320; int dp = i - ro * 320;
  int b = ro / Lr;  int g = ro - b * Lr;
  const u16* src = x + ((size_t)(b * 1000 + g * r) * 320 + dp);
  float s = 0.f;
  for (int j = 0; j < r; j++) s += bf2f(src[(size_t)j * 320]);
  seg[i] = f2bf(s);
}

// ---------------- K3: pack weights transposed+padded: wT[mat][n*320+k] ------
__global__ void k_wprep(const float* __restrict__ wce, const float* __restrict__ wz,
                        const float* __restrict__ wo, u16* __restrict__ wT, int total){
  int i = blockIdx.x * blockDim.x + threadIdx.x;
  if (i >= total) return;
  int mat = i / 102400; int rem = i - mat * 102400;
  int n = rem / 320;    int k = rem - n * 320;
  float v = 0.f;
  if (n < 300 && k < 300){
    const float* src = (mat < 5) ? (wce + mat * 90000) : (mat == 5 ? wz : wo);
    v = src[k * 300 + n];
  }
  wT[i] = f2bf(v);
}

// ---------------- K4: GEMM  C[M,300] = post(A[M,320] @ W[320,320]) ----------
// A: bf16 row-major stride 320. BT: bf16 [n][k] (transposed, padded).
// mode 0: out = (relu(acc)+bias[n])*scale   (contract-expand branch, scale=1/r)
// mode 1: out = tanh(acc)+bias[n]           (z / o branches)
// Tile: BM=128 x BN=320, K-step 32, 8 waves (2Mx4N), wave tile 64x80.
// LDS layout: chunk index = k2*ROWS + row, 16B per chunk -> conflict-free
// ds_read_b128 frag reads (16 consecutive chunks per 16-lane group).
__global__ __launch_bounds__(512) void k_gemm(
    const u16* __restrict__ A, const u16* __restrict__ BT,
    u16* __restrict__ C, const float* __restrict__ bias,
    int mode, float scale)
{
  __shared__ __align__(16) u16 sA[2][512 * 8];    // 4 k2-groups x 128 rows
  __shared__ __align__(16) u16 sB[2][1280 * 8];   // 4 k2-groups x 320 cols
  const int tid  = threadIdx.x;
  const int lane = tid & 63;
  const int wid  = tid >> 6;
  const int wr   = wid >> 2;     // 0..1
  const int wc   = wid & 3;      // 0..3
  const long blockRow = (long)blockIdx.x * 128;

  floatx4 acc[4][5];
  #pragma unroll
  for (int m = 0; m < 4; m++)
    #pragma unroll
    for (int n = 0; n < 5; n++)
      #pragma unroll
      for (int q = 0; q < 4; q++) acc[m][n][q] = 0.f;

  // A staging: chunk c = tid: k2 = c>>7, row = c&127
  const int arow = tid & 127, ak2 = tid >> 7;
  const u16* aptr = A + ((blockRow + arow) * 320 + ak2 * 8);
  // B staging: chunks c0=tid, c1=tid+512, c2=tid+1024 (tid<256); c = k2*320+n
  const int c0 = tid, c1 = tid + 512, c2 = tid + 1024;
  const int k20 = c0 / 320, nn0 = c0 - k20 * 320;
  const int k21 = c1 / 320, nn1 = c1 - k21 * 320;
  const int k22 = c2 / 320, nn2 = c2 - k22 * 320;
  const u16* bptr0 = BT + (nn0 * 320 + k20 * 8);
  const u16* bptr1 = BT + (nn1 * 320 + k21 * 8);
  const u16* bptr2 = BT + (nn2 * 320 + k22 * 8);

  short8 ra, rb0, rb1, rb2;

  // frag read bases (element offsets; chunk*8)
  const int afbase = ((lane >> 4) * 128 + wr * 64 + (lane & 15)) * 8;
  const int bfbase = ((lane >> 4) * 320 + wc * 80 + (lane & 15)) * 8;

  // prologue: tile 0
  ra  = *(const short8*)(aptr);
  rb0 = *(const short8*)(bptr0);
  rb1 = *(const short8*)(bptr1);
  if (tid < 256) rb2 = *(const short8*)(bptr2);
  *(short8*)&sA[0][tid * 8] = ra;
  *(short8*)&sB[0][c0 * 8]  = rb0;
  *(short8*)&sB[0][c1 * 8]  = rb1;
  if (tid < 256) *(short8*)&sB[0][c2 * 8] = rb2;
  __syncthreads();

  #pragma unroll
  for (int kk = 0; kk < 10; kk++){
    const int cur = kk & 1;
    if (kk < 9){   // issue next-tile global loads (latency hidden under MFMA)
      ra  = *(const short8*)(aptr  + (kk + 1) * 32);
      rb0 = *(const short8*)(bptr0 + (kk + 1) * 32);
      rb1 = *(const short8*)(bptr1 + (kk + 1) * 32);
      if (tid < 256) rb2 = *(const short8*)(bptr2 + (kk + 1) * 32);
    }
    short8 af[4], bfr[5];
    #pragma unroll
    for (int m = 0; m < 4; m++)
      af[m] = *(const short8*)&sA[cur][afbase + m * 128];
    #pragma unroll
    for (int n = 0; n < 5; n++)
      bfr[n] = *(const short8*)&sB[cur][bfbase + n * 128];
    #pragma unroll
    for (int m = 0; m < 4; m++)
      #pragma unroll
      for (int n = 0; n < 5; n++)
        acc[m][n] = __builtin_amdgcn_mfma_f32_16x16x32_bf16(af[m], bfr[n], acc[m][n], 0, 0, 0);
    if (kk < 9){   // write next tile into the other buffer (safe: last read kk-1)
      const int nb = cur ^ 1;
      *(short8*)&sA[nb][tid * 8] = ra;
      *(short8*)&sB[nb][c0 * 8]  = rb0;
      *(short8*)&sB[nb][c1 * 8]  = rb1;
      if (tid < 256) *(short8*)&sB[nb][c2 * 8] = rb2;
    }
    __syncthreads();
  }

  // epilogue: D[row][col]: col = lane&15, row = (lane>>4)*4 + reg  (16x16 frag)
  const int colbase = wc * 80 + (lane & 15);
  const int rowbase = wr * 64 + ((lane >> 4) << 2);
  #pragma unroll
  for (int m = 0; m < 4; m++){
    #pragma unroll
    for (int n = 0; n < 5; n++){
      const int gcol = colbase + n * 16;
      if (gcol < 300){
        const float bv = bias[gcol];
        #pragma unroll
        for (int reg = 0; reg < 4; reg++){
          const long grow = blockRow + rowbase + m * 16 + reg;
          float v = acc[m][n][reg];
          if (mode == 0) v = (fmaxf(v, 0.f) + bv) * scale;
          else           v = tanhf(v) + bv;
          C[grow * 300 + gcol] = f2bf(v);
        }
      }
    }
  }
}

// ---------------- gate MLP helper -------------------------------------------
__device__ __forceinline__ float gate_eval(
    float p0, float p1, float p2, float p3, float p4,
    const float W1[3][5], const float W2[3], const float B1[3], float B2)
{
  float acc2 = B2;
  #pragma unroll
  for (int t = 0; t < 3; t++){
    float u = W1[t][0]*p0 + W1[t][1]*p1 + W1[t][2]*p2 + W1[t][3]*p3 + W1[t][4]*p4 + B1[t];
    acc2 += W2[t] * fmaxf(u, 0.f);
  }
  return fmaxf(acc2, 0.f);
}

// ---------------- S1: per-chunk scan composites (A,B) -----------------------
// c_end = A*c_start + B over 50 steps of c = g*c + (1-g)*z
__global__ void k_scan1(const u16* __restrict__ t0, const u16* __restrict__ t1,
    const u16* __restrict__ t2, const u16* __restrict__ t3, const u16* __restrict__ t4,
    const u16* __restrict__ z,
    const float* __restrict__ w1, const float* __restrict__ b1,
    const float* __restrict__ w2, const float* __restrict__ b2,
    float* __restrict__ cA, float* __restrict__ cB, int total)
{
  int i = blockIdx.x * blockDim.x + threadIdx.x;
  if (i >= total) return;
  int d = i % 300; int rest = i / 300; int ch = rest % 20; int b = rest / 20;
  float W1[3][5], W2[3], B1[3];
  #pragma unroll
  for (int t = 0; t < 3; t++){
    #pragma unroll
    for (int s = 0; s < 5; s++) W1[t][s] = w1[t * 5 + s];
    W2[t] = w2[t]; B1[t] = b1[t * 300 + d];
  }
  const float B2 = b2[d];
  float Ac = 1.f, Bc = 0.f;
  const int l0 = ch * 50;
  for (int l = l0; l < l0 + 50; l++){
    float p0 = bf2f(t0[(size_t)(b * 1000 + l)        * 300 + d]);
    float p1 = bf2f(t1[(size_t)(b * 500  + (l >> 1)) * 300 + d]);
    float p2 = bf2f(t2[(size_t)(b * 250  + (l >> 2)) * 300 + d]);
    float p3 = bf2f(t3[(size_t)(b * 100  + l / 10)   * 300 + d]);
    float p4 = bf2f(t4[(size_t)(b * 40   + l / 25)   * 300 + d]);
    float g  = gate_eval(p0, p1, p2, p3, p4, W1, W2, B1, B2);
    float zv = bf2f(z[(size_t)(b * 1000 + l) * 300 + d]);
    Ac = g * Ac;
    Bc = g * Bc + (1.f - g) * zv;
  }
  cA[ch * 19200 + b * 300 + d] = Ac;
  cB[ch * 19200 + b * 300 + d] = Bc;
}

// ---------------- S2: combine 20 chunk composites -> chunk-initial c --------
__global__ void k_scan2(const float* __restrict__ cA, const float* __restrict__ cB,
                        float* __restrict__ cinit, int total){
  int i = blockIdx.x * blockDim.x + threadIdx.x;
  if (i >= total) return;
  float c = 0.f;
  for (int ch = 0; ch < 20; ch++){
    cinit[ch * 19200 + i] = c;
    c = cA[ch * 19200 + i] * c + cB[ch * 19200 + i];
  }
}

// ---------------- S3: final scan + output h = o*c ---------------------------
__global__ void k_scan3(const u16* __restrict__ t0, const u16* __restrict__ t1,
    const u16* __restrict__ t2, const u16* __restrict__ t3, const u16* __restrict__ t4,
    const u16* __restrict__ z, const u16* __restrict__ o,
    const float* __restrict__ cinit,
    const float* __restrict__ w1, const float* __restrict__ b1,
    const float* __restrict__ w2, const float* __restrict__ b2,
    float* __restrict__ out, int total)
{
  int i = blockIdx.x * blockDim.x + threadIdx.x;
  if (i >= total) return;
  int d = i % 300; int rest = i / 300; int ch = rest % 20; int b = rest / 20;
  float W1[3][5], W2[3], B1[3];
  #pragma unroll
  for (int t = 0; t < 3; t++){
    #pragma unroll
    for (int s = 0; s < 5; s++) W1[t][s] = w1[t * 5 + s];
    W2[t] = w2[t]; B1[t] = b1[t * 300 + d];
  }
  const float B2 = b2[d];
  float c = cinit[ch * 19200 + b * 300 + d];
  const int l0 = ch * 50;
  for (int l = l0; l < l0 + 50; l++){
    float p0 = bf2f(t0[(size_t)(b * 1000 + l)        * 300 + d]);
    float p1 = bf2f(t1[(size_t)(b * 500  + (l >> 1)) * 300 + d]);
    float p2 = bf2f(t2[(size_t)(b * 250  + (l >> 2)) * 300 + d]);
    float p3 = bf2f(t3[(size_t)(b * 100  + l / 10)   * 300 + d]);
    float p4 = bf2f(t4[(size_t)(b * 40   + l / 25)   * 300 + d]);
    float g  = gate_eval(p0, p1, p2, p3, p4, W1, W2, B1, B2);
    float zv = bf2f(z[(size_t)(b * 1000 + l) * 300 + d]);
    c = g * c + (1.f - g) * zv;
    float ov = bf2f(o[(size_t)(b * 1000 + l) * 300 + d]);
    out[(size_t)(b * 1000 + l) * 300 + d] = ov * c;
  }
}

extern "C" void kernel_launch(void* const* d_in, const int* in_sizes, int n_in,
                              void* d_out, int out_size, void* d_ws, size_t ws_size,
                              hipStream_t stream){
  const int*   article = (const int*)  d_in[0];
  const float* emb     = (const float*)d_in[1];
  const float* w_ce    = (const float*)d_in[2];
  const float* b_ce    = (const float*)d_in[3];
  const float* w1      = (const float*)d_in[4];
  const float* b1      = (const float*)d_in[5];
  const float* w2      = (const float*)d_in[6];
  const float* b2      = (const float*)d_in[7];
  const float* wz      = (const float*)d_in[8];
  const float* bz      = (const float*)d_in[9];
  const float* wo      = (const float*)d_in[10];
  const float* bo      = (const float*)d_in[11];
  float* out = (float*)d_out;
  char*  ws  = (char*)d_ws;

  // workspace layout (bytes, all 256-aligned)
  u16* x    = (u16*)(ws + 0UL);          // 64000x320 bf16  = 40,960,000
  u16* s2   = (u16*)(ws + 40960000UL);   // 32000x320       = 20,480,000
  u16* s4   = (u16*)(ws + 61440000UL);   // 16000x320       = 10,240,000
  u16* s10  = (u16*)(ws + 71680000UL);   //  6400x320       =  4,096,000
  u16* s25  = (u16*)(ws + 75776000UL);   //  2560x320       =  1,638,400
  u16* wT   = (u16*)(ws + 77414400UL);   // 7x320x320       =  1,433,600
  u16* t0   = (u16*)(ws + 78848000UL);   // 64000x300       = 38,400,000
  u16* t1   = (u16*)(ws + 117248000UL);  // 32000x300       = 19,200,000
  u16* t2   = (u16*)(ws + 136448000UL);  // 16000x300       =  9,600,000
  u16* t3   = (u16*)(ws + 146048000UL);  //  6400x300       =  3,840,000
  u16* t4   = (u16*)(ws + 149888000UL);  //  2560x300       =  1,536,000
  u16* zb   = (u16*)(ws + 151424000UL);  // 64000x300       = 38,400,000
  u16* ob   = (u16*)(ws + 189824000UL);  // 64000x300       = 38,400,000
  float* cA = (float*)(ws + 228224000UL);// 20x19200 f32    =  1,536,000
  float* cB = (float*)(ws + 229760000UL);//                  =  1,536,000
  float* ci = (float*)(ws + 231296000UL);//                  =  1,536,000
  (void)ws_size; (void)in_sizes; (void)n_in; (void)out_size;

  k_gather<<<80000, 256, 0, stream>>>(article, emb, x, 64000 * 320);
  k_segsum<<<40000, 256, 0, stream>>>(x, s2,  2, 500, 32000 * 320);
  k_segsum<<<20000, 256, 0, stream>>>(x, s4,  4, 250, 16000 * 320);
  k_segsum<<< 8000, 256, 0, stream>>>(x, s10, 10, 100, 6400 * 320);
  k_segsum<<< 3200, 256, 0, stream>>>(x, s25, 25, 40,  2560 * 320);
  k_wprep <<< 2800, 256, 0, stream>>>(w_ce, wz, wo, wT, 716800);

  k_gemm<<<500, 512, 0, stream>>>(x,   wT + 0 * 102400, t0, b_ce + 0,    0, 1.0f);
  k_gemm<<<250, 512, 0, stream>>>(s2,  wT + 1 * 102400, t1, b_ce + 300,  0, 0.5f);
  k_gemm<<<125, 512, 0, stream>>>(s4,  wT + 2 * 102400, t2, b_ce + 600,  0, 0.25f);
  k_gemm<<< 50, 512, 0, stream>>>(s10, wT + 3 * 102400, t3, b_ce + 900,  0, 0.1f);
  k_gemm<<< 20, 512, 0, stream>>>(s25, wT + 4 * 102400, t4, b_ce + 1200, 0, 0.04f);
  k_gemm<<<500, 512, 0, stream>>>(x,   wT + 5 * 102400, zb, bz, 1, 1.0f);
  k_gemm<<<500, 512, 0, stream>>>(x,   wT + 6 * 102400, ob, bo, 1, 1.0f);

  k_scan1<<<1500, 256, 0, stream>>>(t0, t1, t2, t3, t4, zb, w1, b1, w2, b2, cA, cB, 384000);
  k_scan2<<<  75, 256, 0, stream>>>(cA, cB, ci, 19200);
  k_scan3<<<1500, 256, 0, stream>>>(t0, t1, t2, t3, t4, zb, ob, ci, w1, b1, w2, b2, out, 384000);
}

// Round 2
// 375.316 us; speedup vs baseline: 1.2594x; 1.2594x over previous
//
#include <hip/hip_runtime.h>
#include <hip/hip_bf16.h>

typedef unsigned short u16;
typedef unsigned int   u32;
typedef __attribute__((ext_vector_type(8))) short short8;
typedef __attribute__((ext_vector_type(4))) float floatx4;
typedef __attribute__((ext_vector_type(4))) unsigned short u16x4;

__device__ __forceinline__ u16 f2bf(float f){
  u32 x = __float_as_uint(f);
  u32 r = (x + 0x7fffu + ((x >> 16) & 1u)) >> 16;   // RNE
  return (u16)r;
}
__device__ __forceinline__ float bf2f(u16 u){
  return __uint_as_float(((u32)u) << 16);
}

// B=64, L=1000, D=300 padded to 320; V=50000
// ---------------- K1: gather + bf16 cast (vectorized), zero-pad [300,320) ---
// thread = (row, j) with j indexing 4-element chunks; 80 chunks/row (75 real).
__global__ void k_gather4(const int* __restrict__ idx, const float* __restrict__ emb,
                          u16* __restrict__ x, int total){
  int i = blockIdx.x * blockDim.x + threadIdx.x;
  if (i >= total) return;
  int row = i / 80; int j = i - row * 80;
  u16x4 o;
  if (j < 75){
    const float4 v = *(const float4*)(emb + (size_t)idx[row] * 300 + j * 4);
    o[0] = f2bf(v.x); o[1] = f2bf(v.y); o[2] = f2bf(v.z); o[3] = f2bf(v.w);
  } else {
    o[0] = 0; o[1] = 0; o[2] = 0; o[3] = 0;
  }
  *(u16x4*)(x + (size_t)row * 320 + j * 4) = o;
}

// ---------------- K2: ALL segment sums in one pass ---------------------------
// thread = (b, window w of 100 l-values, d4 = 4-col group). 100 is divisible
// by 2,4,10,25 and windows start at multiples of 100 -> all groups align.
// Reads x once (41MB), writes s2+s4+s10+s25.
__global__ void k_segsum_all(const u16* __restrict__ x,
                             u16* __restrict__ s2, u16* __restrict__ s4,
                             u16* __restrict__ s10, u16* __restrict__ s25, int total){
  int i = blockIdx.x * blockDim.x + threadIdx.x;
  if (i >= total) return;
  int d4 = i % 80; int rest = i / 80; int w = rest % 10; int b = rest / 10;
  const int dcol = d4 * 4;
  const u16* src = x + ((size_t)(b * 1000 + w * 100) * 320 + dcol);
  float a2[4] = {0,0,0,0}, a4[4] = {0,0,0,0}, a10[4] = {0,0,0,0}, a25[4] = {0,0,0,0};
  #pragma unroll
  for (int l = 0; l < 100; l++){
    u16x4 v = *(const u16x4*)(src + (size_t)l * 320);
    #pragma unroll
    for (int q = 0; q < 4; q++){
      float f = bf2f(v[q]);
      a2[q] += f; a4[q] += f; a10[q] += f; a25[q] += f;
    }
    if ((l & 1) == 1){
      u16x4 o; 
      #pragma unroll
      for (int q = 0; q < 4; q++){ o[q] = f2bf(a2[q]); a2[q] = 0.f; }
      *(u16x4*)(s2 + ((size_t)(b * 500 + w * 50 + (l >> 1)) * 320 + dcol)) = o;
    }
    if ((l & 3) == 3){
      u16x4 o;
      #pragma unroll
      for (int q = 0; q < 4; q++){ o[q] = f2bf(a4[q]); a4[q] = 0.f; }
      *(u16x4*)(s4 + ((size_t)(b * 250 + w * 25 + (l >> 2)) * 320 + dcol)) = o;
    }
    if (l % 10 == 9){
      u16x4 o;
      #pragma unroll
      for (int q = 0; q < 4; q++){ o[q] = f2bf(a10[q]); a10[q] = 0.f; }
      *(u16x4*)(s10 + ((size_t)(b * 100 + w * 10 + l / 10) * 320 + dcol)) = o;
    }
    if (l % 25 == 24){
      u16x4 o;
      #pragma unroll
      for (int q = 0; q < 4; q++){ o[q] = f2bf(a25[q]); a25[q] = 0.f; }
      *(u16x4*)(s25 + ((size_t)(b * 40 + w * 4 + l / 25) * 320 + dcol)) = o;
    }
  }
}

// ---------------- K3: pack weights transposed+padded: wT[mat][n*320+k] ------
__global__ void k_wprep(const float* __restrict__ wce, const float* __restrict__ wz,
                        const float* __restrict__ wo, u16* __restrict__ wT, int total){
  int i = blockIdx.x * blockDim.x + threadIdx.x;
  if (i >= total) return;
  int mat = i / 102400; int rem = i - mat * 102400;
  int n = rem / 320;    int k = rem - n * 320;
  float v = 0.f;
  if (n < 300 && k < 300){
    const float* src = (mat < 5) ? (wce + mat * 90000) : (mat == 5 ? wz : wo);
    v = src[k * 300 + n];
  }
  wT[i] = f2bf(v);
}

// ---------------- GEMM core (device inline) ----------------------------------
// C[M,300] = post(A[M,320] @ W[320,320]); A row-major stride 320, BT: [n][k].
// Tile BM=128 x BN=320, K-step 32, 8 waves (2Mx4N), wave tile 64x80.
__device__ __forceinline__ void gemm_body(
    const u16* __restrict__ A, const u16* __restrict__ BT,
    u16* __restrict__ C, const float* __restrict__ bias,
    int mode, float scale, long blockRow,
    u16* sAbuf, u16* sBbuf)
{
  // sAbuf: 2*512*8 u16 ; sBbuf: 2*1280*8 u16
  u16 (*sA)[512 * 8]  = (u16(*)[512 * 8])sAbuf;
  u16 (*sB)[1280 * 8] = (u16(*)[1280 * 8])sBbuf;
  const int tid  = threadIdx.x;
  const int lane = tid & 63;
  const int wid  = tid >> 6;
  const int wr   = wid >> 2;
  const int wc   = wid & 3;

  floatx4 acc[4][5];
  #pragma unroll
  for (int m = 0; m < 4; m++)
    #pragma unroll
    for (int n = 0; n < 5; n++)
      #pragma unroll
      for (int q = 0; q < 4; q++) acc[m][n][q] = 0.f;

  const int arow = tid & 127, ak2 = tid >> 7;
  const u16* aptr = A + ((blockRow + arow) * 320 + ak2 * 8);
  const int c0 = tid, c1 = tid + 512, c2 = tid + 1024;
  const int k20 = c0 / 320, nn0 = c0 - k20 * 320;
  const int k21 = c1 / 320, nn1 = c1 - k21 * 320;
  const int k22 = c2 / 320, nn2 = c2 - k22 * 320;
  const u16* bptr0 = BT + (nn0 * 320 + k20 * 8);
  const u16* bptr1 = BT + (nn1 * 320 + k21 * 8);
  const u16* bptr2 = BT + (nn2 * 320 + k22 * 8);

  short8 ra, rb0, rb1, rb2;
  const int afbase = ((lane >> 4) * 128 + wr * 64 + (lane & 15)) * 8;
  const int bfbase = ((lane >> 4) * 320 + wc * 80 + (lane & 15)) * 8;

  ra  = *(const short8*)(aptr);
  rb0 = *(const short8*)(bptr0);
  rb1 = *(const short8*)(bptr1);
  if (tid < 256) rb2 = *(const short8*)(bptr2);
  *(short8*)&sA[0][tid * 8] = ra;
  *(short8*)&sB[0][c0 * 8]  = rb0;
  *(short8*)&sB[0][c1 * 8]  = rb1;
  if (tid < 256) *(short8*)&sB[0][c2 * 8] = rb2;
  __syncthreads();

  #pragma unroll
  for (int kk = 0; kk < 10; kk++){
    const int cur = kk & 1;
    if (kk < 9){
      ra  = *(const short8*)(aptr  + (kk + 1) * 32);
      rb0 = *(const short8*)(bptr0 + (kk + 1) * 32);
      rb1 = *(const short8*)(bptr1 + (kk + 1) * 32);
      if (tid < 256) rb2 = *(const short8*)(bptr2 + (kk + 1) * 32);
    }
    short8 af[4], bfr[5];
    #pragma unroll
    for (int m = 0; m < 4; m++)
      af[m] = *(const short8*)&sA[cur][afbase + m * 128];
    #pragma unroll
    for (int n = 0; n < 5; n++)
      bfr[n] = *(const short8*)&sB[cur][bfbase + n * 128];
    #pragma unroll
    for (int m = 0; m < 4; m++)
      #pragma unroll
      for (int n = 0; n < 5; n++)
        acc[m][n] = __builtin_amdgcn_mfma_f32_16x16x32_bf16(af[m], bfr[n], acc[m][n], 0, 0, 0);
    if (kk < 9){
      const int nb = cur ^ 1;
      *(short8*)&sA[nb][tid * 8] = ra;
      *(short8*)&sB[nb][c0 * 8]  = rb0;
      *(short8*)&sB[nb][c1 * 8]  = rb1;
      if (tid < 256) *(short8*)&sB[nb][c2 * 8] = rb2;
    }
    __syncthreads();
  }

  const int colbase = wc * 80 + (lane & 15);
  const int rowbase = wr * 64 + ((lane >> 4) << 2);
  #pragma unroll
  for (int m = 0; m < 4; m++){
    #pragma unroll
    for (int n = 0; n < 5; n++){
      const int gcol = colbase + n * 16;
      if (gcol < 300){
        const float bv = bias[gcol];
        #pragma unroll
        for (int reg = 0; reg < 4; reg++){
          const long grow = blockRow + rowbase + m * 16 + reg;
          float v = acc[m][n][reg];
          if (mode == 0) v = (fmaxf(v, 0.f) + bv) * scale;
          else           v = tanhf(v) + bv;
          C[grow * 300 + gcol] = f2bf(v);
        }
      }
    }
  }
}

__global__ __launch_bounds__(512) void k_gemm(
    const u16* __restrict__ A, const u16* __restrict__ BT,
    u16* __restrict__ C, const float* __restrict__ bias,
    int mode, float scale)
{
  __shared__ __align__(16) u16 sA[2][512 * 8];
  __shared__ __align__(16) u16 sB[2][1280 * 8];
  gemm_body(A, BT, C, bias, mode, scale, (long)blockIdx.x * 128, &sA[0][0], &sB[0][0]);
}

// Fused t0/z/o GEMM. Blocks are XCD-pinned so the 3 members of a trio
// (same A tile, different W) run back-to-back on one XCD -> A L2-shared.
__global__ __launch_bounds__(512) void k_gemm3(
    const u16* __restrict__ A, const u16* __restrict__ wT,
    u16* __restrict__ t0, u16* __restrict__ zb, u16* __restrict__ ob,
    const float* __restrict__ bce0, const float* __restrict__ bz,
    const float* __restrict__ bo)
{
  const int xcd = blockIdx.x & 7;
  const int j   = blockIdx.x >> 3;     // 0..188 per XCD (grid 1512)
  const int t   = xcd * 63 + j / 3;    // trio = A-tile index
  const int m   = j % 3;               // member = which weight matrix
  if (t >= 500) return;
  __shared__ __align__(16) u16 sA[2][512 * 8];
  __shared__ __align__(16) u16 sB[2][1280 * 8];
  const u16* BT = wT + (m == 0 ? 0 : (m == 1 ? 5 : 6)) * 102400;
  u16* C = (m == 0) ? t0 : (m == 1 ? zb : ob);
  const float* bias = (m == 0) ? bce0 : (m == 1 ? bz : bo);
  gemm_body(A, BT, C, bias, (m == 0) ? 0 : 1, 1.0f, (long)t * 128, &sA[0][0], &sB[0][0]);
}

// ---------------- gate MLP helper -------------------------------------------
__device__ __forceinline__ float gate_eval(
    float p0, float p1, float p2, float p3, float p4,
    const float W1[3][5], const float W2[3], const float B1[3], float B2)
{
  float acc2 = B2;
  #pragma unroll
  for (int t = 0; t < 3; t++){
    float u = W1[t][0]*p0 + W1[t][1]*p1 + W1[t][2]*p2 + W1[t][3]*p3 + W1[t][4]*p4 + B1[t];
    acc2 += W2[t] * fmaxf(u, 0.f);
  }
  return fmaxf(acc2, 0.f);
}

// ---------------- S1: per-chunk scan composites (A,B) -----------------------
__global__ void k_scan1(const u16* __restrict__ t0, const u16* __restrict__ t1,
    const u16* __restrict__ t2, const u16* __restrict__ t3, const u16* __restrict__ t4,
    const u16* __restrict__ z,
    const float* __restrict__ w1, const float* __restrict__ b1,
    const float* __restrict__ w2, const float* __restrict__ b2,
    float* __restrict__ cA, float* __restrict__ cB, int total)
{
  int i = blockIdx.x * blockDim.x + threadIdx.x;
  if (i >= total) return;
  int d = i % 300; int rest = i / 300; int ch = rest % 20; int b = rest / 20;
  float W1[3][5], W2[3], B1[3];
  #pragma unroll
  for (int t = 0; t < 3; t++){
    #pragma unroll
    for (int s = 0; s < 5; s++) W1[t][s] = w1[t * 5 + s];
    W2[t] = w2[t]; B1[t] = b1[t * 300 + d];
  }
  const float B2 = b2[d];
  float Ac = 1.f, Bc = 0.f;
  const int l0 = ch * 50;
  for (int l = l0; l < l0 + 50; l++){
    float p0 = bf2f(t0[(size_t)(b * 1000 + l)        * 300 + d]);
    float p1 = bf2f(t1[(size_t)(b * 500  + (l >> 1)) * 300 + d]);
    float p2 = bf2f(t2[(size_t)(b * 250  + (l >> 2)) * 300 + d]);
    float p3 = bf2f(t3[(size_t)(b * 100  + l / 10)   * 300 + d]);
    float p4 = bf2f(t4[(size_t)(b * 40   + l / 25)   * 300 + d]);
    float g  = gate_eval(p0, p1, p2, p3, p4, W1, W2, B1, B2);
    float zv = bf2f(z[(size_t)(b * 1000 + l) * 300 + d]);
    Ac = g * Ac;
    Bc = g * Bc + (1.f - g) * zv;
  }
  cA[ch * 19200 + b * 300 + d] = Ac;
  cB[ch * 19200 + b * 300 + d] = Bc;
}

// ---------------- S2: combine 20 chunk composites -> chunk-initial c --------
__global__ void k_scan2(const float* __restrict__ cA, const float* __restrict__ cB,
                        float* __restrict__ cinit, int total){
  int i = blockIdx.x * blockDim.x + threadIdx.x;
  if (i >= total) return;
  float c = 0.f;
  for (int ch = 0; ch < 20; ch++){
    cinit[ch * 19200 + i] = c;
    c = cA[ch * 19200 + i] * c + cB[ch * 19200 + i];
  }
}

// ---------------- S3: final scan + output h = o*c ---------------------------
__global__ void k_scan3(const u16* __restrict__ t0, const u16* __restrict__ t1,
    const u16* __restrict__ t2, const u16* __restrict__ t3, const u16* __restrict__ t4,
    const u16* __restrict__ z, const u16* __restrict__ o,
    const float* __restrict__ cinit,
    const float* __restrict__ w1, const float* __restrict__ b1,
    const float* __restrict__ w2, const float* __restrict__ b2,
    float* __restrict__ out, int total)
{
  int i = blockIdx.x * blockDim.x + threadIdx.x;
  if (i >= total) return;
  int d = i % 300; int rest = i / 300; int ch = rest % 20; int b = rest / 20;
  float W1[3][5], W2[3], B1[3];
  #pragma unroll
  for (int t = 0; t < 3; t++){
    #pragma unroll
    for (int s = 0; s < 5; s++) W1[t][s] = w1[t * 5 + s];
    W2[t] = w2[t]; B1[t] = b1[t * 300 + d];
  }
  const float B2 = b2[d];
  float c = cinit[ch * 19200 + b * 300 + d];
  const int l0 = ch * 50;
  for (int l = l0; l < l0 + 50; l++){
    float p0 = bf2f(t0[(size_t)(b * 1000 + l)        * 300 + d]);
    float p1 = bf2f(t1[(size_t)(b * 500  + (l >> 1)) * 300 + d]);
    float p2 = bf2f(t2[(size_t)(b * 250  + (l >> 2)) * 300 + d]);
    float p3 = bf2f(t3[(size_t)(b * 100  + l / 10)   * 300 + d]);
    float p4 = bf2f(t4[(size_t)(b * 40   + l / 25)   * 300 + d]);
    float g  = gate_eval(p0, p1, p2, p3, p4, W1, W2, B1, B2);
    float zv = bf2f(z[(size_t)(b * 1000 + l) * 300 + d]);
    c = g * c + (1.f - g) * zv;
    float ov = bf2f(o[(size_t)(b * 1000 + l) * 300 + d]);
    out[(size_t)(b * 1000 + l) * 300 + d] = ov * c;
  }
}

extern "C" void kernel_launch(void* const* d_in, const int* in_sizes, int n_in,
                              void* d_out, int out_size, void* d_ws, size_t ws_size,
                              hipStream_t stream){
  const int*   article = (const int*)  d_in[0];
  const float* emb     = (const float*)d_in[1];
  const float* w_ce    = (const float*)d_in[2];
  const float* b_ce    = (const float*)d_in[3];
  const float* w1      = (const float*)d_in[4];
  const float* b1      = (const float*)d_in[5];
  const float* w2      = (const float*)d_in[6];
  const float* b2      = (const float*)d_in[7];
  const float* wz      = (const float*)d_in[8];
  const float* bz      = (const float*)d_in[9];
  const float* wo      = (const float*)d_in[10];
  const float* bo      = (const float*)d_in[11];
  float* out = (float*)d_out;
  char*  ws  = (char*)d_ws;

  // workspace layout (bytes, all 256-aligned)
  u16* x    = (u16*)(ws + 0UL);          // 64000x320 bf16  = 40,960,000
  u16* s2   = (u16*)(ws + 40960000UL);   // 32000x320       = 20,480,000
  u16* s4   = (u16*)(ws + 61440000UL);   // 16000x320       = 10,240,000
  u16* s10  = (u16*)(ws + 71680000UL);   //  6400x320       =  4,096,000
  u16* s25  = (u16*)(ws + 75776000UL);   //  2560x320       =  1,638,400
  u16* wT   = (u16*)(ws + 77414400UL);   // 7x320x320       =  1,433,600
  u16* t0   = (u16*)(ws + 78848000UL);   // 64000x300       = 38,400,000
  u16* t1   = (u16*)(ws + 117248000UL);  // 32000x300       = 19,200,000
  u16* t2   = (u16*)(ws + 136448000UL);  // 16000x300       =  9,600,000
  u16* t3   = (u16*)(ws + 146048000UL);  //  6400x300       =  3,840,000
  u16* t4   = (u16*)(ws + 149888000UL);  //  2560x300       =  1,536,000
  u16* zb   = (u16*)(ws + 151424000UL);  // 64000x300       = 38,400,000
  u16* ob   = (u16*)(ws + 189824000UL);  // 64000x300       = 38,400,000
  float* cA = (float*)(ws + 228224000UL);// 20x19200 f32    =  1,536,000
  float* cB = (float*)(ws + 229760000UL);//                  =  1,536,000
  float* ci = (float*)(ws + 231296000UL);//                  =  1,536,000
  (void)ws_size; (void)in_sizes; (void)n_in; (void)out_size;

  k_wprep  <<< 2800, 256, 0, stream>>>(w_ce, wz, wo, wT, 716800);
  k_gather4<<<20000, 256, 0, stream>>>(article, emb, x, 64000 * 80);
  k_segsum_all<<<200, 256, 0, stream>>>(x, s2, s4, s10, s25, 51200);

  k_gemm3<<<1512, 512, 0, stream>>>(x, wT, t0, zb, ob, b_ce + 0, bz, bo);
  k_gemm<<<250, 512, 0, stream>>>(s2,  wT + 1 * 102400, t1, b_ce + 300,  0, 0.5f);
  k_gemm<<<125, 512, 0, stream>>>(s4,  wT + 2 * 102400, t2, b_ce + 600,  0, 0.25f);
  k_gemm<<< 50, 512, 0, stream>>>(s10, wT + 3 * 102400, t3, b_ce + 900,  0, 0.1f);
  k_gemm<<< 20, 512, 0, stream>>>(s25, wT + 4 * 102400, t4, b_ce + 1200, 0, 0.04f);

  k_scan1<<<1500, 256, 0, stream>>>(t0, t1, t2, t3, t4, zb, w1, b1, w2, b2, cA, cB, 384000);
  k_scan2<<<  75, 256, 0, stream>>>(cA, cB, ci, 19200);
  k_scan3<<<1500, 256, 0, stream>>>(t0, t1, t2, t3, t4, zb, ob, ci, w1, b1, w2, b2, out, 384000);
}

// Round 3
// 352.102 us; speedup vs baseline: 1.3425x; 1.0659x over previous
//
#include <hip/hip_runtime.h>
#include <hip/hip_bf16.h>

typedef unsigned short u16;
typedef unsigned int   u32;
typedef __attribute__((ext_vector_type(8))) short short8;
typedef __attribute__((ext_vector_type(4))) float floatx4;
typedef __attribute__((ext_vector_type(4))) unsigned short u16x4;

__device__ __forceinline__ u16 f2bf(float f){
  u32 x = __float_as_uint(f);
  u32 r = (x + 0x7fffu + ((x >> 16) & 1u)) >> 16;   // RNE
  return (u16)r;
}
__device__ __forceinline__ float bf2f(u16 u){
  return __uint_as_float(((u32)u) << 16);
}
// fast tanh: (e-1)/(e+1), e = 2^(2x*log2e). |err| < ~1e-5, invisible in bf16.
__device__ __forceinline__ float tanh_fast(float x){
  float xs = fminf(fmaxf(x, -16.f), 16.f);
  float e  = __builtin_amdgcn_exp2f(xs * 2.8853900817779268f);
  return (e - 1.f) * __builtin_amdgcn_rcpf(e + 1.f);
}

// B=64, L=1000, D=300 padded to 320; V=50000
// ---------------- K1: gather + bf16 cast (vectorized), zero-pad [300,320) ---
__global__ void k_gather4(const int* __restrict__ idx, const float* __restrict__ emb,
                          u16* __restrict__ x, int total){
  int i = blockIdx.x * blockDim.x + threadIdx.x;
  if (i >= total) return;
  int row = i / 80; int j = i - row * 80;
  u16x4 o;
  if (j < 75){
    const float4 v = *(const float4*)(emb + (size_t)idx[row] * 300 + j * 4);
    o[0] = f2bf(v.x); o[1] = f2bf(v.y); o[2] = f2bf(v.z); o[3] = f2bf(v.w);
  } else {
    o[0] = 0; o[1] = 0; o[2] = 0; o[3] = 0;
  }
  *(u16x4*)(x + (size_t)row * 320 + j * 4) = o;
}

// ---------------- K2: ALL segment sums in one pass ---------------------------
__global__ void k_segsum_all(const u16* __restrict__ x,
                             u16* __restrict__ s2, u16* __restrict__ s4,
                             u16* __restrict__ s10, u16* __restrict__ s25, int total){
  int i = blockIdx.x * blockDim.x + threadIdx.x;
  if (i >= total) return;
  int d4 = i % 80; int rest = i / 80; int w = rest % 10; int b = rest / 10;
  const int dcol = d4 * 4;
  const u16* src = x + ((size_t)(b * 1000 + w * 100) * 320 + dcol);
  float a2[4] = {0,0,0,0}, a4[4] = {0,0,0,0}, a10[4] = {0,0,0,0}, a25[4] = {0,0,0,0};
  #pragma unroll
  for (int l = 0; l < 100; l++){
    u16x4 v = *(const u16x4*)(src + (size_t)l * 320);
    #pragma unroll
    for (int q = 0; q < 4; q++){
      float f = bf2f(v[q]);
      a2[q] += f; a4[q] += f; a10[q] += f; a25[q] += f;
    }
    if ((l & 1) == 1){
      u16x4 o;
      #pragma unroll
      for (int q = 0; q < 4; q++){ o[q] = f2bf(a2[q]); a2[q] = 0.f; }
      *(u16x4*)(s2 + ((size_t)(b * 500 + w * 50 + (l >> 1)) * 320 + dcol)) = o;
    }
    if ((l & 3) == 3){
      u16x4 o;
      #pragma unroll
      for (int q = 0; q < 4; q++){ o[q] = f2bf(a4[q]); a4[q] = 0.f; }
      *(u16x4*)(s4 + ((size_t)(b * 250 + w * 25 + (l >> 2)) * 320 + dcol)) = o;
    }
    if (l % 10 == 9){
      u16x4 o;
      #pragma unroll
      for (int q = 0; q < 4; q++){ o[q] = f2bf(a10[q]); a10[q] = 0.f; }
      *(u16x4*)(s10 + ((size_t)(b * 100 + w * 10 + l / 10) * 320 + dcol)) = o;
    }
    if (l % 25 == 24){
      u16x4 o;
      #pragma unroll
      for (int q = 0; q < 4; q++){ o[q] = f2bf(a25[q]); a25[q] = 0.f; }
      *(u16x4*)(s25 + ((size_t)(b * 40 + w * 4 + l / 25) * 320 + dcol)) = o;
    }
  }
}

// ---------------- K3: pack weights transposed+padded: wT[mat][n*320+k] ------
__global__ void k_wprep(const float* __restrict__ wce, const float* __restrict__ wz,
                        const float* __restrict__ wo, u16* __restrict__ wT, int total){
  int i = blockIdx.x * blockDim.x + threadIdx.x;
  if (i >= total) return;
  int mat = i / 102400; int rem = i - mat * 102400;
  int n = rem / 320;    int k = rem - n * 320;
  float v = 0.f;
  if (n < 300 && k < 300){
    const float* src = (mat < 5) ? (wce + mat * 90000) : (mat == 5 ? wz : wo);
    v = src[k * 300 + n];
  }
  wT[i] = f2bf(v);
}

// ---------------- K4: ALL GEMMs, no-LDS streaming MFMA ----------------------
// C[M,300] = post(A[M,320] @ W[320,320]).  A row-major stride 320 (K contig),
// BT = W^T row-major [n][k].  MFMA frags loaded DIRECTLY from global (each
// frag-load: 64 lanes x 16B = 16 full 64B lines; W + trio-shared A are L2/L1
// resident).  No LDS, no barriers; register double-buffer across K-steps.
// Block = 256 thr = 4 waves (1M x 4N), tile 64 x 320; wave tile 64 x 80.
__global__ __launch_bounds__(256, 3) void k_gemm_all(
    const u16* __restrict__ x,  const u16* __restrict__ s2,
    const u16* __restrict__ s4, const u16* __restrict__ s10,
    const u16* __restrict__ s25,const u16* __restrict__ wT,
    u16* __restrict__ t0, u16* __restrict__ t1, u16* __restrict__ t2,
    u16* __restrict__ t3, u16* __restrict__ t4,
    u16* __restrict__ zb, u16* __restrict__ ob,
    const float* __restrict__ b_ce, const float* __restrict__ bz,
    const float* __restrict__ bo)
{
  const int bid = blockIdx.x;
  const u16* A; const u16* BT; u16* C; const float* bias;
  int mode; float scale; long tileRow;
  if (bid < 890){                       // small GEMMs first (fill tail)
    if (bid < 500)      { A=s2;  BT=wT+1*102400; C=t1; bias=b_ce+300;  mode=0; scale=0.5f;  tileRow=(long)bid*64; }
    else if (bid < 750) { A=s4;  BT=wT+2*102400; C=t2; bias=b_ce+600;  mode=0; scale=0.25f; tileRow=(long)(bid-500)*64; }
    else if (bid < 850) { A=s10; BT=wT+3*102400; C=t3; bias=b_ce+900;  mode=0; scale=0.1f;  tileRow=(long)(bid-750)*64; }
    else                { A=s25; BT=wT+4*102400; C=t4; bias=b_ce+1200; mode=0; scale=0.04f; tileRow=(long)(bid-850)*64; }
  } else {                              // t0/z/o trios, XCD-pinned (A L2-shared)
    const int g = bid - 890; const int xcd = g & 7; const int j = g >> 3;
    const int t = xcd * 125 + j / 3; const int m = j % 3;
    tileRow = (long)t * 64; A = x;
    if (m == 0)      { BT = wT;            C = t0; bias = b_ce; mode = 0; scale = 1.f; }
    else if (m == 1) { BT = wT + 5*102400; C = zb; bias = bz;   mode = 1; scale = 1.f; }
    else             { BT = wT + 6*102400; C = ob; bias = bo;   mode = 1; scale = 1.f; }
  }

  const int lane = threadIdx.x & 63;
  const int wc   = threadIdx.x >> 6;          // 0..3 (N-wave)
  // frag base addrs (element units): A[row][k2*8..], BT[col][k2*8..]
  const u16* aF = A  + ((size_t)(tileRow + (lane & 15))) * 320 + ((lane >> 4) * 8);
  const u16* bF = BT + ((size_t)(wc * 80 + (lane & 15))) * 320 + ((lane >> 4) * 8);

  floatx4 acc[4][5];
  #pragma unroll
  for (int m = 0; m < 4; m++)
    #pragma unroll
    for (int n = 0; n < 5; n++)
      #pragma unroll
      for (int q = 0; q < 4; q++) acc[m][n][q] = 0.f;

  short8 ca[4], cb[5], na[4], nb[5];
  #pragma unroll
  for (int m = 0; m < 4; m++) ca[m] = *(const short8*)(aF + m * 16 * 320);
  #pragma unroll
  for (int n = 0; n < 5; n++) cb[n] = *(const short8*)(bF + n * 16 * 320);

  #pragma unroll
  for (int kk = 0; kk < 10; kk++){
    if (kk < 9){
      #pragma unroll
      for (int m = 0; m < 4; m++) na[m] = *(const short8*)(aF + m * 16 * 320 + (kk + 1) * 32);
      #pragma unroll
      for (int n = 0; n < 5; n++) nb[n] = *(const short8*)(bF + n * 16 * 320 + (kk + 1) * 32);
    }
    #pragma unroll
    for (int m = 0; m < 4; m++)
      #pragma unroll
      for (int n = 0; n < 5; n++)
        acc[m][n] = __builtin_amdgcn_mfma_f32_16x16x32_bf16(ca[m], cb[n], acc[m][n], 0, 0, 0);
    #pragma unroll
    for (int m = 0; m < 4; m++) ca[m] = na[m];
    #pragma unroll
    for (int n = 0; n < 5; n++) cb[n] = nb[n];
  }

  // epilogue: D[row][col]: col = lane&15 (+n*16+wc*80), row = (lane>>4)*4+reg
  const int colbase = wc * 80 + (lane & 15);
  const int rowbase = (lane >> 4) << 2;
  #pragma unroll
  for (int m = 0; m < 4; m++){
    #pragma unroll
    for (int n = 0; n < 5; n++){
      const int gcol = colbase + n * 16;
      if (gcol < 300){
        const float bv = bias[gcol];
        #pragma unroll
        for (int reg = 0; reg < 4; reg++){
          const long grow = tileRow + rowbase + m * 16 + reg;
          float v = acc[m][n][reg];
          if (mode == 0) v = (fmaxf(v, 0.f) + bv) * scale;
          else           v = tanh_fast(v) + bv;
          C[grow * 300 + gcol] = f2bf(v);
        }
      }
    }
  }
}

// ---------------- gate MLP helper -------------------------------------------
__device__ __forceinline__ float gate_eval(
    float p0, float p1, float p2, float p3, float p4,
    const float W1[3][5], const float W2[3], const float B1[3], float B2)
{
  float acc2 = B2;
  #pragma unroll
  for (int t = 0; t < 3; t++){
    float u = W1[t][0]*p0 + W1[t][1]*p1 + W1[t][2]*p2 + W1[t][3]*p3 + W1[t][4]*p4 + B1[t];
    acc2 += W2[t] * fmaxf(u, 0.f);
  }
  return fmaxf(acc2, 0.f);
}

// ---------------- S1: per-chunk scan composites (A,B) -----------------------
__global__ void k_scan1(const u16* __restrict__ t0, const u16* __restrict__ t1,
    const u16* __restrict__ t2, const u16* __restrict__ t3, const u16* __restrict__ t4,
    const u16* __restrict__ z,
    const float* __restrict__ w1, const float* __restrict__ b1,
    const float* __restrict__ w2, const float* __restrict__ b2,
    float* __restrict__ cA, float* __restrict__ cB, int total)
{
  int i = blockIdx.x * blockDim.x + threadIdx.x;
  if (i >= total) return;
  int d = i % 300; int rest = i / 300; int ch = rest % 20; int b = rest / 20;
  float W1[3][5], W2[3], B1[3];
  #pragma unroll
  for (int t = 0; t < 3; t++){
    #pragma unroll
    for (int s = 0; s < 5; s++) W1[t][s] = w1[t * 5 + s];
    W2[t] = w2[t]; B1[t] = b1[t * 300 + d];
  }
  const float B2 = b2[d];
  float Ac = 1.f, Bc = 0.f;
  const int l0 = ch * 50;
  for (int l = l0; l < l0 + 50; l++){
    float p0 = bf2f(t0[(size_t)(b * 1000 + l)        * 300 + d]);
    float p1 = bf2f(t1[(size_t)(b * 500  + (l >> 1)) * 300 + d]);
    float p2 = bf2f(t2[(size_t)(b * 250  + (l >> 2)) * 300 + d]);
    float p3 = bf2f(t3[(size_t)(b * 100  + l / 10)   * 300 + d]);
    float p4 = bf2f(t4[(size_t)(b * 40   + l / 25)   * 300 + d]);
    float g  = gate_eval(p0, p1, p2, p3, p4, W1, W2, B1, B2);
    float zv = bf2f(z[(size_t)(b * 1000 + l) * 300 + d]);
    Ac = g * Ac;
    Bc = g * Bc + (1.f - g) * zv;
  }
  cA[ch * 19200 + b * 300 + d] = Ac;
  cB[ch * 19200 + b * 300 + d] = Bc;
}

// ---------------- S2: combine 20 chunk composites -> chunk-initial c --------
__global__ void k_scan2(const float* __restrict__ cA, const float* __restrict__ cB,
                        float* __restrict__ cinit, int total){
  int i = blockIdx.x * blockDim.x + threadIdx.x;
  if (i >= total) return;
  float c = 0.f;
  for (int ch = 0; ch < 20; ch++){
    cinit[ch * 19200 + i] = c;
    c = cA[ch * 19200 + i] * c + cB[ch * 19200 + i];
  }
}

// ---------------- S3: final scan + output h = o*c ---------------------------
__global__ void k_scan3(const u16* __restrict__ t0, const u16* __restrict__ t1,
    const u16* __restrict__ t2, const u16* __restrict__ t3, const u16* __restrict__ t4,
    const u16* __restrict__ z, const u16* __restrict__ o,
    const float* __restrict__ cinit,
    const float* __restrict__ w1, const float* __restrict__ b1,
    const float* __restrict__ w2, const float* __restrict__ b2,
    float* __restrict__ out, int total)
{
  int i = blockIdx.x * blockDim.x + threadIdx.x;
  if (i >= total) return;
  int d = i % 300; int rest = i / 300; int ch = rest % 20; int b = rest / 20;
  float W1[3][5], W2[3], B1[3];
  #pragma unroll
  for (int t = 0; t < 3; t++){
    #pragma unroll
    for (int s = 0; s < 5; s++) W1[t][s] = w1[t * 5 + s];
    W2[t] = w2[t]; B1[t] = b1[t * 300 + d];
  }
  const float B2 = b2[d];
  float c = cinit[ch * 19200 + b * 300 + d];
  const int l0 = ch * 50;
  for (int l = l0; l < l0 + 50; l++){
    float p0 = bf2f(t0[(size_t)(b * 1000 + l)        * 300 + d]);
    float p1 = bf2f(t1[(size_t)(b * 500  + (l >> 1)) * 300 + d]);
    float p2 = bf2f(t2[(size_t)(b * 250  + (l >> 2)) * 300 + d]);
    float p3 = bf2f(t3[(size_t)(b * 100  + l / 10)   * 300 + d]);
    float p4 = bf2f(t4[(size_t)(b * 40   + l / 25)   * 300 + d]);
    float g  = gate_eval(p0, p1, p2, p3, p4, W1, W2, B1, B2);
    float zv = bf2f(z[(size_t)(b * 1000 + l) * 300 + d]);
    c = g * c + (1.f - g) * zv;
    float ov = bf2f(o[(size_t)(b * 1000 + l) * 300 + d]);
    out[(size_t)(b * 1000 + l) * 300 + d] = ov * c;
  }
}

extern "C" void kernel_launch(void* const* d_in, const int* in_sizes, int n_in,
                              void* d_out, int out_size, void* d_ws, size_t ws_size,
                              hipStream_t stream){
  const int*   article = (const int*)  d_in[0];
  const float* emb     = (const float*)d_in[1];
  const float* w_ce    = (const float*)d_in[2];
  const float* b_ce    = (const float*)d_in[3];
  const float* w1      = (const float*)d_in[4];
  const float* b1      = (const float*)d_in[5];
  const float* w2      = (const float*)d_in[6];
  const float* b2      = (const float*)d_in[7];
  const float* wz      = (const float*)d_in[8];
  const float* bz      = (const float*)d_in[9];
  const float* wo      = (const float*)d_in[10];
  const float* bo      = (const float*)d_in[11];
  float* out = (float*)d_out;
  char*  ws  = (char*)d_ws;

  // workspace layout (bytes, all 256-aligned)
  u16* x    = (u16*)(ws + 0UL);          // 64000x320 bf16  = 40,960,000
  u16* s2   = (u16*)(ws + 40960000UL);   // 32000x320       = 20,480,000
  u16* s4   = (u16*)(ws + 61440000UL);   // 16000x320       = 10,240,000
  u16* s10  = (u16*)(ws + 71680000UL);   //  6400x320       =  4,096,000
  u16* s25  = (u16*)(ws + 75776000UL);   //  2560x320       =  1,638,400
  u16* wT   = (u16*)(ws + 77414400UL);   // 7x320x320       =  1,433,600
  u16* t0   = (u16*)(ws + 78848000UL);   // 64000x300       = 38,400,000
  u16* t1   = (u16*)(ws + 117248000UL);  // 32000x300       = 19,200,000
  u16* t2   = (u16*)(ws + 136448000UL);  // 16000x300       =  9,600,000
  u16* t3   = (u16*)(ws + 146048000UL);  //  6400x300       =  3,840,000
  u16* t4   = (u16*)(ws + 149888000UL);  //  2560x300       =  1,536,000
  u16* zb   = (u16*)(ws + 151424000UL);  // 64000x300       = 38,400,000
  u16* ob   = (u16*)(ws + 189824000UL);  // 64000x300       = 38,400,000
  float* cA = (float*)(ws + 228224000UL);// 20x19200 f32    =  1,536,000
  float* cB = (float*)(ws + 229760000UL);//                  =  1,536,000
  float* ci = (float*)(ws + 231296000UL);//                  =  1,536,000
  (void)ws_size; (void)in_sizes; (void)n_in; (void)out_size;

  k_wprep  <<< 2800, 256, 0, stream>>>(w_ce, wz, wo, wT, 716800);
  k_gather4<<<20000, 256, 0, stream>>>(article, emb, x, 64000 * 80);
  k_segsum_all<<<200, 256, 0, stream>>>(x, s2, s4, s10, s25, 51200);

  k_gemm_all<<<3890, 256, 0, stream>>>(x, s2, s4, s10, s25, wT,
                                       t0, t1, t2, t3, t4, zb, ob,
                                       b_ce, bz, bo);

  k_scan1<<<1500, 256, 0, stream>>>(t0, t1, t2, t3, t4, zb, w1, b1, w2, b2, cA, cB, 384000);
  k_scan2<<<  75, 256, 0, stream>>>(cA, cB, ci, 19200);
  k_scan3<<<1500, 256, 0, stream>>>(t0, t1, t2, t3, t4, zb, ob, ci, w1, b1, w2, b2, out, 384000);
}